// Round 6
// baseline (3346.151 us; speedup 1.0000x reference)
//
#include <hip/hip_runtime.h>
#include <hip/hip_bf16.h>

// B=2, S=4096, D=1024, H=16, HD=64, M=512, L=1024, HID=2816, 8 scan steps.
// R5 failed: hipLaunchCooperativeKernel(512 blocks) silently rejected ->
// scan never ran (out ~= 0). R6: NORMAL launch of 256 persistent blocks
// (<= 256 CUs; 4 waves + 32KB LDS => all blocks resident under any packing)
// with a manual sense-reversing grid barrier (device-scope atomics +
// __threadfence both sides). Phases: P1 om@wm(+rs1) | P2 w13 128-tile
// (rms fused, stride loop 352 tiles) | P3 w2 (silu fused, +rs2) |
// P4 kmvm (rms fused, 2 tiles/block) | P5 attention (mem rope fused,
// blocks 0/1 also zero rs1/rs2).

#define NSTEP 8

typedef __hip_bfloat16 bf16;
typedef _Float16 f16;
typedef __attribute__((ext_vector_type(8))) short short8;
typedef __attribute__((ext_vector_type(8))) _Float16 f16x8;
typedef __attribute__((ext_vector_type(2))) _Float16 f16x2;
typedef __attribute__((ext_vector_type(4))) float floatx4;

// ---------------- dtype probe ----------------
__global__ void probe_dtype(const void* x, int* flag) {
  int lane = threadIdx.x;
  unsigned short v = ((const unsigned short*)x)[2 * lane];
  int e = (v >> 7) & 0xFF;
  bool sane = (e >= 100 && e <= 140);
  unsigned long long m = __ballot(sane);
  if (lane == 0) flag[0] = (__popcll(m) >= 40) ? 1 : 0;  // 1 = bf16 inputs
}

__device__ __forceinline__ float load_any(const void* p, long i, int isbf) {
  return isbf ? __bfloat162float(((const bf16*)p)[i]) : ((const float*)p)[i];
}

// ---------------- batched weight transpose ----------------
struct TArg { const void* src; const void* scl; bf16* dst; int K, N, start; };
struct TArgs { TArg a[10]; };

__global__ __launch_bounds__(256) void transpose_all(TArgs ta, const int* flagp) {
  __shared__ float tile[32][33];
  int isbf = flagp[0];
  int bid = blockIdx.x;
  int z = 0;
  while (z < 9 && bid >= ta.a[z + 1].start) ++z;
  const TArg& e = ta.a[z];
  int local = bid - e.start;
  int tnx = e.N >> 5;
  int bx = local % tnx, by = local / tnx;
  int tx = threadIdx.x & 31, ty = threadIdx.x >> 5;
  int n = bx * 32 + tx;
#pragma unroll
  for (int i = 0; i < 4; i++) {
    int k = by * 32 + ty + i * 8;
    tile[ty + i * 8][tx] = load_any(e.src, (long)k * e.N + n, isbf);
  }
  __syncthreads();
  int k2 = by * 32 + tx;
  float s = e.scl ? load_any(e.scl, k2, isbf) : 1.f;
#pragma unroll
  for (int i = 0; i < 4; i++) {
    int n2 = bx * 32 + ty + i * 8;
    e.dst[(long)n2 * e.K + k2] = __float2bfloat16(tile[tx][ty + i * 8] * s);
  }
}

// ---------------- prep: x cast, cos/sin, om init, rs/bar zero ----------------
__global__ __launch_bounds__(256) void prep(const void* x, const void* fc,
                                            const void* fs, const void* om0,
                                            bf16* xb, float* cosf, float* sinf,
                                            bf16* om_bf, float* rs1, float* rs2,
                                            int* bar, const int* flagp) {
  long idx = (long)blockIdx.x * 256 + threadIdx.x;
  int isbf = flagp[0];
  if (idx < 8388608) { xb[idx] = __float2bfloat16(load_any(x, idx, isbf)); return; }
  long i = idx - 8388608;
  if (i < 32768) { cosf[i] = load_any(fc, i, isbf); return; }
  i -= 32768;
  if (i < 32768) { sinf[i] = load_any(fs, i, isbf); return; }
  i -= 32768;
  if (i < 1048576) { om_bf[i] = __float2bfloat16(load_any(om0, i & 524287, isbf)); return; }
  i -= 1048576;
  if (i < 1024) { rs1[i] = 0.f; return; }
  i -= 1024;
  if (i < 1024) { rs2[i] = 0.f; return; }
  i -= 1024;
  if (i < 128) bar[i] = 0;
}

// ---------------- 128x128 MFMA GEMM (qkv upfront, final wo) ----------------
__global__ __launch_bounds__(256) void gemm128(
    const bf16* __restrict__ A, const bf16* __restrict__ WT,
    void* __restrict__ out, const int* __restrict__ flagp,
    int N, int K, int out_mode) {
  __shared__ char smem[32768];
  int tid = threadIdx.x;
  int w = tid >> 6, lane = tid & 63;
  int C0 = blockIdx.x * 128, R0 = blockIdx.y * 128;
  int wm = (w >> 1) * 64, wn = (w & 1) * 64;
  int g = lane >> 4, n16 = lane & 15;
  floatx4 acc[4][4] = {};
  int lr = lane >> 3, lc = lane & 7;

  for (int k0 = 0; k0 < K; k0 += 64) {
    __syncthreads();
#pragma unroll
    for (int i = 0; i < 4; ++i) {
      int m = w * 32 + i * 8 + lr;
      int cg = lc ^ (m & 7);
      const bf16* ga = A + (size_t)(R0 + m) * K + k0 + cg * 8;
      const bf16* gb = WT + (size_t)(C0 + m) * K + k0 + cg * 8;
      __builtin_amdgcn_global_load_lds(
          (const __attribute__((address_space(1))) void*)ga,
          (__attribute__((address_space(3))) void*)(smem + (w * 32 + i * 8) * 128),
          16, 0, 0);
      __builtin_amdgcn_global_load_lds(
          (const __attribute__((address_space(1))) void*)gb,
          (__attribute__((address_space(3))) void*)(smem + 16384 + (w * 32 + i * 8) * 128),
          16, 0, 0);
    }
    __syncthreads();
#pragma unroll
    for (int kk = 0; kk < 2; ++kk) {
      short8 af[4], bfr[4];
#pragma unroll
      for (int i = 0; i < 4; ++i) {
        int ml = wm + i * 16 + n16;
        af[i] = *(const short8*)(smem + (ml * 8 + ((kk * 4 + g) ^ (ml & 7))) * 16);
        int nl = wn + i * 16 + n16;
        bfr[i] = *(const short8*)(smem + 16384 + (nl * 8 + ((kk * 4 + g) ^ (nl & 7))) * 16);
      }
#pragma unroll
      for (int i = 0; i < 4; ++i)
#pragma unroll
        for (int j = 0; j < 4; ++j)
          acc[i][j] = __builtin_amdgcn_mfma_f32_16x16x32_bf16(af[i], bfr[j], acc[i][j], 0, 0, 0);
    }
  }
  int isbf = flagp[0];
#pragma unroll
  for (int i = 0; i < 4; ++i)
#pragma unroll
    for (int j = 0; j < 4; ++j) {
      int row = R0 + wm + i * 16 + g * 4;
      int col = C0 + wn + j * 16 + n16;
#pragma unroll
      for (int rg = 0; rg < 4; ++rg) {
        float v = acc[i][j][rg];
        long off = (long)(row + rg) * N + col;
        if (out_mode == 0) ((float*)out)[off] = v;
        else if (out_mode == 1) ((f16*)out)[off] = (f16)v;
        else {
          if (isbf) ((bf16*)out)[off] = __float2bfloat16(v);
          else ((float*)out)[off] = v;
        }
      }
    }
}

// ---------------- rope (x side, all 8 slabs, upfront) ----------------
__global__ __launch_bounds__(256) void rope_x(
    const f16* __restrict__ qkv, const float* __restrict__ cosf,
    const float* __restrict__ sinf, f16* __restrict__ q_x,
    f16* __restrict__ k_x, f16* __restrict__ v_xT) {
  __shared__ f16 tile[64][72];
  int pt = blockIdx.x;  // pos tile 0..7
  int t = blockIdx.y;   // 0..7
  int bh = blockIdx.z;  // 0..31
  int b = bh >> 4, h = bh & 15;
  int tid = threadIdx.x;
  int i = tid & 31, p0 = tid >> 5;
  size_t slab = (size_t)t * 32 + bh;
#pragma unroll
  for (int j = 0; j < 8; ++j) {
    int pl = p0 + j * 8;
    int m = pt * 64 + pl;
    int pos = 512 + m;
    long base = ((long)b * 4096 + t * 512 + m) * 3072 + h * 64 + 2 * i;
    float c = cosf[pos * 32 + i], s = sinf[pos * 32 + i];
    float q0 = (float)qkv[base], q1 = (float)qkv[base + 1];
    f16x2 qw; qw.x = (f16)((q0 * c - q1 * s) * 0.125f);
    qw.y = (f16)((q0 * s + q1 * c) * 0.125f);
    *(f16x2*)(q_x + (slab * 512 + m) * 64 + 2 * i) = qw;
    float k0 = (float)qkv[base + 1024], k1 = (float)qkv[base + 1025];
    f16x2 kw; kw.x = (f16)(k0 * c - k1 * s); kw.y = (f16)(k0 * s + k1 * c);
    *(f16x2*)(k_x + (slab * 512 + m) * 64 + 2 * i) = kw;
    tile[2 * i][pl] = qkv[base + 2048];
    tile[2 * i + 1][pl] = qkv[base + 2049];
  }
  __syncthreads();
#pragma unroll
  for (int j = 0; j < 8; ++j) {
    int d = p0 + j * 8;
    f16x2 vv; vv.x = tile[d][2 * i]; vv.y = tile[d][2 * i + 1];
    *(f16x2*)(v_xT + (slab * 64 + d) * 512 + pt * 64 + 2 * i) = vv;
  }
}

// ---------------- manual grid barrier (256 co-resident blocks) ----------------
#define NBLK 256
__device__ __forceinline__ void gbar(int* bar) {
  __syncthreads();
  if (threadIdx.x == 0) {
    __threadfence();  // release: publish this block's stores
    int* cnt = bar;
    int* gen = bar + 64;  // 256B apart
    int g = __hip_atomic_load(gen, __ATOMIC_RELAXED, __HIP_MEMORY_SCOPE_AGENT);
    int old = __hip_atomic_fetch_add(cnt, 1, __ATOMIC_ACQ_REL, __HIP_MEMORY_SCOPE_AGENT);
    if (old == NBLK - 1) {
      __hip_atomic_store(cnt, 0, __ATOMIC_RELAXED, __HIP_MEMORY_SCOPE_AGENT);
      __hip_atomic_fetch_add(gen, 1, __ATOMIC_ACQ_REL, __HIP_MEMORY_SCOPE_AGENT);
    } else {
      while (__hip_atomic_load(gen, __ATOMIC_ACQUIRE, __HIP_MEMORY_SCOPE_AGENT) == g)
        __builtin_amdgcn_s_sleep(2);
    }
    __threadfence();  // acquire: invalidate stale cache before next phase reads
  }
  __syncthreads();
}

// ---------------- persistent scan loop (normal launch, 256 blocks) ----------
__global__ __launch_bounds__(256) void scan_loop(
    const bf16* __restrict__ wmT, const bf16* __restrict__ w13T,
    const bf16* __restrict__ w2T, const bf16* __restrict__ wkmvmT,
    const f16* __restrict__ q_x, const f16* __restrict__ k_x,
    const f16* __restrict__ v_xT, const float* __restrict__ cosf,
    const float* __restrict__ sinf, bf16* __restrict__ om_bf,
    bf16* __restrict__ outs_bf, float* __restrict__ om2a,
    float* __restrict__ g13, float* __restrict__ om2b,
    f16* __restrict__ mkv, float* __restrict__ rs1, float* __restrict__ rs2,
    int* __restrict__ bar) {
  __shared__ char smem[32768];
  int bid = blockIdx.x, tid = threadIdx.x;
  int w = tid >> 6, lane = tid & 63;
  int g = lane >> 4, n16 = lane & 15;
  int wm_ = w >> 1, wn_ = w & 1;

  for (int t = 0; t < NSTEP; ++t) {
    // ===== P1: om2a = om_bf @ wmT (64-tile) + rs1 row-sumsq =====
    {
      int C0 = (bid & 15) * 64, R0 = (bid >> 4) * 64;
      floatx4 acc[2][2] = {};
      int am0 = tid >> 3, ac0 = tid & 7;
      int am1 = (tid + 256) >> 3, ac1 = tid & 7;
      long grow0 = R0 + am0, grow1 = R0 + am1;
      long bn0 = (long)(C0 + am0) * 1024, bn1 = (long)(C0 + am1) * 1024;
      int lofa0 = (am0 * 8 + (ac0 ^ (am0 & 7))) * 16;
      int lofa1 = (am1 * 8 + (ac1 ^ (am1 & 7))) * 16;
      for (int k0 = 0; k0 < 1024; k0 += 64) {
        uint4 va0 = *(const uint4*)(om_bf + grow0 * 1024 + k0 + ac0 * 8);
        uint4 va1 = *(const uint4*)(om_bf + grow1 * 1024 + k0 + ac1 * 8);
        uint4 vb0 = *(const uint4*)(wmT + bn0 + k0 + ac0 * 8);
        uint4 vb1 = *(const uint4*)(wmT + bn1 + k0 + ac1 * 8);
        __syncthreads();
        *(uint4*)(smem + lofa0) = va0;
        *(uint4*)(smem + lofa1) = va1;
        *(uint4*)(smem + 8192 + lofa0) = vb0;
        *(uint4*)(smem + 8192 + lofa1) = vb1;
        __syncthreads();
#pragma unroll
        for (int kki = 0; kki < 2; ++kki) {
          int cb = kki * 4 + g;
          short8 af[2], bfr[2];
#pragma unroll
          for (int i = 0; i < 2; ++i) {
            int ml = wm_ * 32 + i * 16 + n16;
            af[i] = *(const short8*)(smem + (ml * 8 + (cb ^ (ml & 7))) * 16);
            int nl = wn_ * 32 + i * 16 + n16;
            bfr[i] = *(const short8*)(smem + 8192 + (nl * 8 + (cb ^ (nl & 7))) * 16);
          }
#pragma unroll
          for (int i = 0; i < 2; ++i)
#pragma unroll
            for (int j = 0; j < 2; ++j)
              acc[i][j] = __builtin_amdgcn_mfma_f32_16x16x32_bf16(af[i], bfr[j], acc[i][j], 0, 0, 0);
        }
      }
      __syncthreads();
      float* rsl = (float*)(smem + 16384);
      if (tid < 64) rsl[tid] = 0.f;
      __syncthreads();
#pragma unroll
      for (int i = 0; i < 2; ++i)
#pragma unroll
        for (int rg = 0; rg < 4; ++rg) {
          int rl = wm_ * 32 + i * 16 + g * 4 + rg;
          float sq = 0.f;
#pragma unroll
          for (int j = 0; j < 2; ++j) {
            float v = acc[i][j][rg];
            sq += v * v;
            om2a[(long)(R0 + rl) * 1024 + C0 + wn_ * 32 + j * 16 + n16] = v;
          }
          atomicAdd(&rsl[rl], sq);
        }
      __syncthreads();
      if (tid < 64) atomicAdd(&rs1[R0 + tid], rsl[tid]);
    }
    gbar(bar);

    // ===== P2: g13 = rmsnorm(om2a) @ w13T (128-tile, scale fused) =====
    for (int tile = bid; tile < 352; tile += NBLK) {
      int C0 = (tile % 44) * 128, R0 = (tile / 44) * 128;
      int wmm = (w >> 1) * 64, wnn = (w & 1) * 64;
      floatx4 acc[4][4] = {};
      int lr = lane >> 3, lc = lane & 7;
      int ams[4], acs[4];
      float sca[4];
#pragma unroll
      for (int i = 0; i < 4; ++i) {
        int id = tid + 256 * i;
        ams[i] = id >> 3;
        acs[i] = id & 7;
        sca[i] = rsqrtf(rs1[R0 + ams[i]] * (1.f / 1024.f) + 1e-5f);
      }
      for (int k0 = 0; k0 < 1024; k0 += 64) {
        uint4 av[4];
#pragma unroll
        for (int i = 0; i < 4; ++i) {
          const float* ap = om2a + (size_t)(R0 + ams[i]) * 1024 + k0 + acs[i] * 8;
          float4 x0 = *(const float4*)ap, x1 = *(const float4*)(ap + 4);
          union { bf16 b[8]; uint4 u; } pk;
          pk.b[0] = __float2bfloat16(x0.x * sca[i]);
          pk.b[1] = __float2bfloat16(x0.y * sca[i]);
          pk.b[2] = __float2bfloat16(x0.z * sca[i]);
          pk.b[3] = __float2bfloat16(x0.w * sca[i]);
          pk.b[4] = __float2bfloat16(x1.x * sca[i]);
          pk.b[5] = __float2bfloat16(x1.y * sca[i]);
          pk.b[6] = __float2bfloat16(x1.z * sca[i]);
          pk.b[7] = __float2bfloat16(x1.w * sca[i]);
          av[i] = pk.u;
        }
        __syncthreads();
#pragma unroll
        for (int i = 0; i < 4; ++i)
          *(uint4*)(smem + (ams[i] * 8 + (acs[i] ^ (ams[i] & 7))) * 16) = av[i];
#pragma unroll
        for (int i = 0; i < 4; ++i) {
          int m = w * 32 + i * 8 + lr;
          int cg = lc ^ (m & 7);
          const bf16* gb = w13T + (size_t)(C0 + m) * 1024 + k0 + cg * 8;
          __builtin_amdgcn_global_load_lds(
              (const __attribute__((address_space(1))) void*)gb,
              (__attribute__((address_space(3))) void*)(smem + 16384 + (w * 32 + i * 8) * 128),
              16, 0, 0);
        }
        __syncthreads();
#pragma unroll
        for (int kk = 0; kk < 2; ++kk) {
          short8 af[4], bfr[4];
#pragma unroll
          for (int i = 0; i < 4; ++i) {
            int ml = wmm + i * 16 + n16;
            af[i] = *(const short8*)(smem + (ml * 8 + ((kk * 4 + g) ^ (ml & 7))) * 16);
            int nl = wnn + i * 16 + n16;
            bfr[i] = *(const short8*)(smem + 16384 + (nl * 8 + ((kk * 4 + g) ^ (nl & 7))) * 16);
          }
#pragma unroll
          for (int i = 0; i < 4; ++i)
#pragma unroll
            for (int j = 0; j < 4; ++j)
              acc[i][j] = __builtin_amdgcn_mfma_f32_16x16x32_bf16(af[i], bfr[j], acc[i][j], 0, 0, 0);
        }
      }
#pragma unroll
      for (int i = 0; i < 4; ++i)
#pragma unroll
        for (int j = 0; j < 4; ++j) {
          int row = R0 + wmm + i * 16 + g * 4;
          int col = C0 + wnn + j * 16 + n16;
#pragma unroll
          for (int rg = 0; rg < 4; ++rg)
            g13[(long)(row + rg) * 5632 + col] = acc[i][j][rg];
        }
      __syncthreads();
    }
    gbar(bar);

    // ===== P3: om2b = om2a + (silu(g1)*g3) @ w2T (+rs2) =====
    {
      int C0 = (bid & 15) * 64, R0 = (bid >> 4) * 64;
      floatx4 acc[2][2] = {};
      int am0 = tid >> 3, ac0 = tid & 7;
      int am1 = (tid + 256) >> 3, ac1 = tid & 7;
      long bn0 = (long)(C0 + am0) * 2816, bn1 = (long)(C0 + am1) * 2816;
      int lofa0 = (am0 * 8 + (ac0 ^ (am0 & 7))) * 16;
      int lofa1 = (am1 * 8 + (ac1 ^ (am1 & 7))) * 16;
      for (int k0 = 0; k0 < 2816; k0 += 64) {
        uint4 va[2];
        int amv[2] = {am0, am1}, acv[2] = {ac0, ac1};
#pragma unroll
        for (int i = 0; i < 2; ++i) {
          const float* g1p = g13 + (size_t)(R0 + amv[i]) * 5632 + k0 + acv[i] * 8;
          const float* g3p = g1p + 2816;
          float4 a0 = *(const float4*)g1p, a1 = *(const float4*)(g1p + 4);
          float4 b0 = *(const float4*)g3p, b1 = *(const float4*)(g3p + 4);
          union { bf16 b[8]; uint4 u; } pk;
          pk.b[0] = __float2bfloat16(a0.x / (1.f + __expf(-a0.x)) * b0.x);
          pk.b[1] = __float2bfloat16(a0.y / (1.f + __expf(-a0.y)) * b0.y);
          pk.b[2] = __float2bfloat16(a0.z / (1.f + __expf(-a0.z)) * b0.z);
          pk.b[3] = __float2bfloat16(a0.w / (1.f + __expf(-a0.w)) * b0.w);
          pk.b[4] = __float2bfloat16(a1.x / (1.f + __expf(-a1.x)) * b1.x);
          pk.b[5] = __float2bfloat16(a1.y / (1.f + __expf(-a1.y)) * b1.y);
          pk.b[6] = __float2bfloat16(a1.z / (1.f + __expf(-a1.z)) * b1.z);
          pk.b[7] = __float2bfloat16(a1.w / (1.f + __expf(-a1.w)) * b1.w);
          va[i] = pk.u;
        }
        uint4 vb0 = *(const uint4*)(w2T + bn0 + k0 + ac0 * 8);
        uint4 vb1 = *(const uint4*)(w2T + bn1 + k0 + ac1 * 8);
        __syncthreads();
        *(uint4*)(smem + lofa0) = va[0];
        *(uint4*)(smem + lofa1) = va[1];
        *(uint4*)(smem + 8192 + lofa0) = vb0;
        *(uint4*)(smem + 8192 + lofa1) = vb1;
        __syncthreads();
#pragma unroll
        for (int kki = 0; kki < 2; ++kki) {
          int cb = kki * 4 + g;
          short8 af[2], bfr[2];
#pragma unroll
          for (int i = 0; i < 2; ++i) {
            int ml = wm_ * 32 + i * 16 + n16;
            af[i] = *(const short8*)(smem + (ml * 8 + (cb ^ (ml & 7))) * 16);
            int nl = wn_ * 32 + i * 16 + n16;
            bfr[i] = *(const short8*)(smem + 8192 + (nl * 8 + (cb ^ (nl & 7))) * 16);
          }
#pragma unroll
          for (int i = 0; i < 2; ++i)
#pragma unroll
            for (int j = 0; j < 2; ++j)
              acc[i][j] = __builtin_amdgcn_mfma_f32_16x16x32_bf16(af[i], bfr[j], acc[i][j], 0, 0, 0);
        }
      }
      __syncthreads();
      float* rsl = (float*)(smem + 16384);
      if (tid < 64) rsl[tid] = 0.f;
      __syncthreads();
#pragma unroll
      for (int i = 0; i < 2; ++i)
#pragma unroll
        for (int rg = 0; rg < 4; ++rg) {
          int rl = wm_ * 32 + i * 16 + g * 4 + rg;
          float sq = 0.f;
#pragma unroll
          for (int j = 0; j < 2; ++j) {
            long off = (long)(R0 + rl) * 1024 + C0 + wn_ * 32 + j * 16 + n16;
            float o2 = om2a[off] + acc[i][j][rg];
            om2b[off] = o2;
            sq += o2 * o2;
          }
          atomicAdd(&rsl[rl], sq);
        }
      __syncthreads();
      if (tid < 64) atomicAdd(&rs2[R0 + tid], rsl[tid]);
    }
    gbar(bar);

    // ===== P4: mkv = rmsnorm(om2b) @ wkmvmT (f16 out), 2 tiles/block =====
#pragma unroll
    for (int half = 0; half < 2; ++half) {
      int tile = bid + half * NBLK;
      int C0 = (tile & 31) * 64, R0 = (tile >> 5) * 64;
      floatx4 acc[2][2] = {};
      int am0 = tid >> 3, ac0 = tid & 7;
      int am1 = (tid + 256) >> 3, ac1 = tid & 7;
      long bn0 = (long)(C0 + am0) * 1024, bn1 = (long)(C0 + am1) * 1024;
      int lofa0 = (am0 * 8 + (ac0 ^ (am0 & 7))) * 16;
      int lofa1 = (am1 * 8 + (ac1 ^ (am1 & 7))) * 16;
      float sc0 = rsqrtf(rs2[R0 + am0] * (1.f / 1024.f) + 1e-5f);
      float sc1 = rsqrtf(rs2[R0 + am1] * (1.f / 1024.f) + 1e-5f);
      for (int k0 = 0; k0 < 1024; k0 += 64) {
        uint4 va[2];
        int amv[2] = {am0, am1}, acv[2] = {ac0, ac1};
        float scv[2] = {sc0, sc1};
#pragma unroll
        for (int i = 0; i < 2; ++i) {
          const float* ap = om2b + (size_t)(R0 + amv[i]) * 1024 + k0 + acv[i] * 8;
          float4 x0 = *(const float4*)ap, x1 = *(const float4*)(ap + 4);
          union { bf16 b[8]; uint4 u; } pk;
          pk.b[0] = __float2bfloat16(x0.x * scv[i]);
          pk.b[1] = __float2bfloat16(x0.y * scv[i]);
          pk.b[2] = __float2bfloat16(x0.z * scv[i]);
          pk.b[3] = __float2bfloat16(x0.w * scv[i]);
          pk.b[4] = __float2bfloat16(x1.x * scv[i]);
          pk.b[5] = __float2bfloat16(x1.y * scv[i]);
          pk.b[6] = __float2bfloat16(x1.z * scv[i]);
          pk.b[7] = __float2bfloat16(x1.w * scv[i]);
          va[i] = pk.u;
        }
        uint4 vb0 = *(const uint4*)(wkmvmT + bn0 + k0 + ac0 * 8);
        uint4 vb1 = *(const uint4*)(wkmvmT + bn1 + k0 + ac1 * 8);
        __syncthreads();
        *(uint4*)(smem + lofa0) = va[0];
        *(uint4*)(smem + lofa1) = va[1];
        *(uint4*)(smem + 8192 + lofa0) = vb0;
        *(uint4*)(smem + 8192 + lofa1) = vb1;
        __syncthreads();
#pragma unroll
        for (int kki = 0; kki < 2; ++kki) {
          int cb = kki * 4 + g;
          short8 af[2], bfr[2];
#pragma unroll
          for (int i = 0; i < 2; ++i) {
            int ml = wm_ * 32 + i * 16 + n16;
            af[i] = *(const short8*)(smem + (ml * 8 + (cb ^ (ml & 7))) * 16);
            int nl = wn_ * 32 + i * 16 + n16;
            bfr[i] = *(const short8*)(smem + 8192 + (nl * 8 + (cb ^ (nl & 7))) * 16);
          }
#pragma unroll
          for (int i = 0; i < 2; ++i)
#pragma unroll
            for (int j = 0; j < 2; ++j)
              acc[i][j] = __builtin_amdgcn_mfma_f32_16x16x32_bf16(af[i], bfr[j], acc[i][j], 0, 0, 0);
        }
      }
#pragma unroll
      for (int i = 0; i < 2; ++i)
#pragma unroll
        for (int j = 0; j < 2; ++j) {
          int row = R0 + wm_ * 32 + i * 16 + g * 4;
          int col = C0 + wn_ * 32 + j * 16 + n16;
#pragma unroll
          for (int rg = 0; rg < 4; ++rg)
            mkv[(long)(row + rg) * 2048 + col] = (f16)acc[i][j][rg];
        }
      __syncthreads();
    }
    gbar(bar);

    // ===== P5: fp16 MFMA flash attention (mem rope fused) =====
    {
      // blocks 0/1 also reset rs1/rs2 for next step (no one reads rs in P5)
      if (bid == 0) {
        rs1[tid] = 0.f; rs1[tid + 256] = 0.f; rs1[tid + 512] = 0.f; rs1[tid + 768] = 0.f;
      } else if (bid == 1) {
        rs2[tid] = 0.f; rs2[tid + 256] = 0.f; rs2[tid + 512] = 0.f; rs2[tid + 768] = 0.f;
      }
      int qt = bid & 7, bh = bid >> 3;
      int batb = bh >> 4, hh = bh & 15;
      int numc = 9 + qt;
      int pos = 512 + qt * 64 + w * 16 + n16;
      size_t slab = (size_t)t * 32 + bh;
      f16x8 qf[2];
      {
        const f16* qp = q_x + (slab * 512 + qt * 64 + w * 16 + n16) * 64 + g * 8;
        qf[0] = *(const f16x8*)(qp);
        qf[1] = *(const f16x8*)(qp + 32);
      }
      floatx4 O[4] = {};
      float mrun = -1e30f, lrun = 0.f;
      int r0 = tid >> 3, c0 = tid & 7;
      int r1 = (tid + 256) >> 3, c1 = tid & 7;
      int lof0 = ((r0 << 3) | (c0 ^ (r0 & 7))) * 16;
      int lof1 = ((r1 << 3) | (c1 ^ (r1 & 7))) * 16;

      auto ld_k = [&](int c, int r, int dc) -> uint4 {
        union { f16x8 h; uint4 u; } cv;
        if (c < 8) {
          int pp = c * 64 + r;
          f16x8 kv = *(const f16x8*)(mkv + ((size_t)(batb * 512 + pp)) * 2048 + hh * 64 + dc * 8);
#pragma unroll
          for (int j = 0; j < 4; ++j) {
            float cs = cosf[pp * 32 + dc * 4 + j], sn = sinf[pp * 32 + dc * 4 + j];
            float a = (float)kv[2 * j], bq = (float)kv[2 * j + 1];
            cv.h[2 * j] = (f16)(a * cs - bq * sn);
            cv.h[2 * j + 1] = (f16)(a * sn + bq * cs);
          }
        } else {
          cv.u = *(const uint4*)(k_x + (slab * 512 + (c - 8) * 64 + r) * 64 + dc * 8);
        }
        return cv.u;
      };
      auto ld_v = [&](int c, int r, int dc) -> uint4 {
        union { f16x8 h; uint4 u; } cv;
        if (c < 8) {
#pragma unroll
          for (int j = 0; j < 8; ++j)
            cv.h[j] = mkv[((size_t)(batb * 512 + c * 64 + dc * 8 + j)) * 2048 + 1024 + hh * 64 + r];
        } else {
          cv.u = *(const uint4*)(v_xT + (slab * 64 + r) * 512 + (c - 8) * 64 + dc * 8);
        }
        return cv.u;
      };

      uint4 kv0 = ld_k(0, r0, c0), kv1 = ld_k(0, r1, c1);
      uint4 vv0 = ld_v(0, r0, c0), vv1 = ld_v(0, r1, c1);
      char* Pw = smem + 16384 + w * 2048;

      for (int c = 0; c < numc; ++c) {
        __syncthreads();
        *(uint4*)(smem + lof0) = kv0;
        *(uint4*)(smem + lof1) = kv1;
        *(uint4*)(smem + 8192 + lof0) = vv0;
        *(uint4*)(smem + 8192 + lof1) = vv1;
        if (c + 1 < numc) {
          kv0 = ld_k(c + 1, r0, c0);
          kv1 = ld_k(c + 1, r1, c1);
          vv0 = ld_v(c + 1, r0, c0);
          vv1 = ld_v(c + 1, r1, c1);
        }
        __syncthreads();

        floatx4 S[4] = {};
#pragma unroll
        for (int kk = 0; kk < 2; ++kk) {
#pragma unroll
          for (int tn = 0; tn < 4; ++tn) {
            int row = tn * 16 + n16;
            f16x8 kf = *(const f16x8*)(smem + (((row << 3) | ((kk * 4 + g) ^ (row & 7))) * 16));
            S[tn] = __builtin_amdgcn_mfma_f32_16x16x32_f16(kf, qf[kk], S[tn], 0, 0, 0);
          }
        }
        if (c == numc - 1) {
          int kb = 512 + (c - 8) * 64;
#pragma unroll
          for (int tn = 0; tn < 4; ++tn)
#pragma unroll
            for (int r = 0; r < 4; ++r) {
              int key = kb + tn * 16 + g * 4 + r;
              if (key > pos) S[tn][r] = -1e30f;
            }
        }
        float smax = -1e30f;
#pragma unroll
        for (int tn = 0; tn < 4; ++tn)
#pragma unroll
          for (int r = 0; r < 4; ++r) smax = fmaxf(smax, S[tn][r]);
        smax = fmaxf(smax, __shfl_xor(smax, 16));
        smax = fmaxf(smax, __shfl_xor(smax, 32));
        float newm = fmaxf(mrun, smax);
        float corr = __expf(mrun - newm);
        mrun = newm;
        float lsum = 0.f;
        f16 pv[16];
#pragma unroll
        for (int tn = 0; tn < 4; ++tn)
#pragma unroll
          for (int r = 0; r < 4; ++r) {
            float p = __expf(S[tn][r] - newm);
            lsum += p;
            pv[tn * 4 + r] = (f16)p;
          }
        lsum += __shfl_xor(lsum, 16);
        lsum += __shfl_xor(lsum, 32);
        lrun = lrun * corr + lsum;
        float cr[4];
#pragma unroll
        for (int r = 0; r < 4; ++r) cr[r] = __shfl(corr, g * 4 + r);
#pragma unroll
        for (int dt = 0; dt < 4; ++dt)
#pragma unroll
          for (int r = 0; r < 4; ++r) O[dt][r] *= cr[r];
#pragma unroll
        for (int tn = 0; tn < 4; ++tn)
#pragma unroll
          for (int r = 0; r < 4; ++r) {
            int kap = tn * 16 + g * 4 + r;
            *(f16*)(Pw + (((n16 << 3) | ((kap >> 3) ^ (n16 & 7))) * 16 + (kap & 7) * 2)) =
                pv[tn * 4 + r];
          }
#pragma unroll
        for (int kk = 0; kk < 2; ++kk) {
          f16x8 pf = *(const f16x8*)(Pw + (((n16 << 3) | ((kk * 4 + g) ^ (n16 & 7))) * 16));
#pragma unroll
          for (int dt = 0; dt < 4; ++dt) {
            int row = dt * 16 + n16;
            f16x8 vf =
                *(const f16x8*)(smem + 8192 + (((row << 3) | ((kk * 4 + g) ^ (row & 7))) * 16));
            O[dt] = __builtin_amdgcn_mfma_f32_16x16x32_f16(pf, vf, O[dt], 0, 0, 0);
          }
        }
      }
      float rl = 1.0f / lrun;
      float rlr[4];
#pragma unroll
      for (int r = 0; r < 4; ++r) rlr[r] = __shfl(rl, g * 4 + r);
#pragma unroll
      for (int dt = 0; dt < 4; ++dt)
#pragma unroll
        for (int r = 0; r < 4; ++r) {
          int qq = qt * 64 + w * 16 + g * 4 + r;
          bf16 v = __float2bfloat16(O[dt][r] * rlr[r]);
          size_t col = hh * 64 + dt * 16 + n16;
          om_bf[((size_t)(batb * 512 + qq)) * 1024 + col] = v;
          outs_bf[((size_t)(batb * 4096 + t * 512 + qq)) * 1024 + col] = v;
        }
    }
    gbar(bar);
  }
}

// ---------------- launch ----------------
extern "C" void kernel_launch(void* const* d_in, const int* in_sizes, int n_in,
                              void* d_out, int out_size, void* d_ws, size_t ws_size,
                              hipStream_t stream) {
  (void)in_sizes; (void)n_in; (void)out_size; (void)ws_size;
  const void* x   = d_in[0];
  const void* fc  = d_in[1];
  const void* fs  = d_in[2];
  const void* wq  = d_in[3];
  const void* wk  = d_in[4];
  const void* wv  = d_in[5];
  const void* wo  = d_in[6];
  const void* wm  = d_in[7];
  const void* wkm = d_in[8];
  const void* wvm = d_in[9];
  const void* w1  = d_in[10];
  const void* w3  = d_in[11];
  const void* w2  = d_in[12];
  const void* fnw = d_in[13];
  const void* mnw = d_in[14];
  const void* om0 = d_in[15];

  char* p = (char*)d_ws;
  auto alloc = [&](size_t bytes) -> char* {
    char* r = p;
    p += (bytes + 255) & ~(size_t)255;
    return r;
  };
  int*   flag    = (int*)alloc(256);
  int*   bar     = (int*)alloc(512);
  bf16*  wqkvT   = (bf16*)alloc((size_t)3 * 1048576 * 2);
  bf16*  wmT     = (bf16*)alloc((size_t)1048576 * 2);
  bf16*  wkmvmT  = (bf16*)alloc((size_t)2 * 1048576 * 2);
  bf16*  w13T    = (bf16*)alloc((size_t)2 * 2883584 * 2);
  bf16*  w2T     = (bf16*)alloc((size_t)2883584 * 2);
  bf16*  woT     = (bf16*)alloc((size_t)1048576 * 2);
  bf16*  xb      = (bf16*)alloc((size_t)8388608 * 2);
  float* cosf    = (float*)alloc((size_t)32768 * 4);
  float* sinf    = (float*)alloc((size_t)32768 * 4);
  bf16*  om_bf   = (bf16*)alloc((size_t)1048576 * 2);
  bf16*  outs_bf = (bf16*)alloc((size_t)8388608 * 2);
  f16*   q_x     = (f16*)alloc((size_t)8 * 32 * 512 * 64 * 2);
  f16*   k_x     = (f16*)alloc((size_t)8 * 32 * 512 * 64 * 2);
  f16*   v_xT    = (f16*)alloc((size_t)8 * 32 * 512 * 64 * 2);
  float* rs1     = (float*)alloc((size_t)1024 * 4);
  float* rs2     = (float*)alloc((size_t)1024 * 4);
  // shared region: qkvf_all (upfront, 50.3 MB) overlaps loop scratch (~35 MB)
  char*  shr     = alloc((size_t)8192 * 3072 * 2);
  f16*   qkvf_all = (f16*)shr;
  char*  lp = shr;
  auto lalloc = [&](size_t bytes) -> char* {
    char* r = lp;
    lp += (bytes + 255) & ~(size_t)255;
    return r;
  };
  float* om2a = (float*)lalloc((size_t)1048576 * 4);
  float* g13  = (float*)lalloc((size_t)5767168 * 4);
  float* om2b = (float*)lalloc((size_t)1048576 * 4);
  f16*   mkv  = (f16*)lalloc((size_t)2097152 * 2);

  dim3 tb(256);
  probe_dtype<<<1, 64, 0, stream>>>(x, flag);

  // batched weight transposes (fnw folded into w1/w3; mnw into wkm/wvm)
  TArgs ta;
  int start = 0;
  auto addT = [&](int i, const void* src, const void* scl, bf16* dst, int K, int N) {
    ta.a[i].src = src; ta.a[i].scl = scl; ta.a[i].dst = dst;
    ta.a[i].K = K; ta.a[i].N = N; ta.a[i].start = start;
    start += (N / 32) * (K / 32);
  };
  addT(0, wq, nullptr, wqkvT, 1024, 1024);
  addT(1, wk, nullptr, wqkvT + 1048576, 1024, 1024);
  addT(2, wv, nullptr, wqkvT + 2 * 1048576, 1024, 1024);
  addT(3, wm, nullptr, wmT, 1024, 1024);
  addT(4, wkm, mnw, wkmvmT, 1024, 1024);
  addT(5, wvm, mnw, wkmvmT + 1048576, 1024, 1024);
  addT(6, w1, fnw, w13T, 1024, 2816);
  addT(7, w3, fnw, w13T + 2816 * 1024, 1024, 2816);
  addT(8, w2, nullptr, w2T, 2816, 1024);
  addT(9, wo, nullptr, woT, 1024, 1024);
  transpose_all<<<start, tb, 0, stream>>>(ta, flag);

  prep<<<37129, tb, 0, stream>>>(x, fc, fs, om0, xb, cosf, sinf, om_bf, rs1, rs2,
                                 bar, flag);

  // hoisted: qkv for all 8 steps, then x-side rope/V-transpose
  gemm128<<<dim3(24, 64), tb, 0, stream>>>(xb, wqkvT, qkvf_all, flag, 3072, 1024, 1);
  rope_x<<<dim3(8, 8, 32), tb, 0, stream>>>(qkvf_all, cosf, sinf, q_x, k_x, v_xT);

  // the whole 8-step scan: one persistent kernel, manual grid barrier
  scan_loop<<<dim3(NBLK), tb, 0, stream>>>(wmT, w13T, w2T, wkmvmT, q_x, k_x, v_xT,
                                           cosf, sinf, om_bf, outs_bf, om2a, g13,
                                           om2b, mkv, rs1, rs2, bar);

  gemm128<<<dim3(8, 64), tb, 0, stream>>>(outs_bf, woT, d_out, flag, 1024, 1024, 2);
}

// Round 7
// 2962.253 us; speedup vs baseline: 1.1296x; 1.1296x over previous
//
#include <hip/hip_runtime.h>
#include <hip/hip_bf16.h>

// B=2, S=4096, D=1024, H=16, HD=64, M=512, L=1024, HID=2816, 8 scan steps.
// R6: persistent scan passed but 3109us — P5's fused rope/V-gather staging did
// ~48 scalar loads/thread/chunk at 1 wave/SIMD (87% idle, FETCH 3x). R7: restore
// R4's coalesced attention staging: new P4b phase (rope_mem-style LDS transpose
// mkv -> k_mem/v_memT, 256 blocks), P5 = R4 attn_mfma vector loads. Spin backoff
// s_sleep(64). Phases: P1 om@wm(+rs1) | P2 w13 | P3 w2(silu fused,+rs2) |
// P4 kmvm | P4b rope_mem | P5 attention.

#define NSTEP 8

typedef __hip_bfloat16 bf16;
typedef _Float16 f16;
typedef __attribute__((ext_vector_type(8))) short short8;
typedef __attribute__((ext_vector_type(8))) _Float16 f16x8;
typedef __attribute__((ext_vector_type(2))) _Float16 f16x2;
typedef __attribute__((ext_vector_type(4))) float floatx4;

// ---------------- dtype probe ----------------
__global__ void probe_dtype(const void* x, int* flag) {
  int lane = threadIdx.x;
  unsigned short v = ((const unsigned short*)x)[2 * lane];
  int e = (v >> 7) & 0xFF;
  bool sane = (e >= 100 && e <= 140);
  unsigned long long m = __ballot(sane);
  if (lane == 0) flag[0] = (__popcll(m) >= 40) ? 1 : 0;  // 1 = bf16 inputs
}

__device__ __forceinline__ float load_any(const void* p, long i, int isbf) {
  return isbf ? __bfloat162float(((const bf16*)p)[i]) : ((const float*)p)[i];
}

// ---------------- batched weight transpose ----------------
struct TArg { const void* src; const void* scl; bf16* dst; int K, N, start; };
struct TArgs { TArg a[10]; };

__global__ __launch_bounds__(256) void transpose_all(TArgs ta, const int* flagp) {
  __shared__ float tile[32][33];
  int isbf = flagp[0];
  int bid = blockIdx.x;
  int z = 0;
  while (z < 9 && bid >= ta.a[z + 1].start) ++z;
  const TArg& e = ta.a[z];
  int local = bid - e.start;
  int tnx = e.N >> 5;
  int bx = local % tnx, by = local / tnx;
  int tx = threadIdx.x & 31, ty = threadIdx.x >> 5;
  int n = bx * 32 + tx;
#pragma unroll
  for (int i = 0; i < 4; i++) {
    int k = by * 32 + ty + i * 8;
    tile[ty + i * 8][tx] = load_any(e.src, (long)k * e.N + n, isbf);
  }
  __syncthreads();
  int k2 = by * 32 + tx;
  float s = e.scl ? load_any(e.scl, k2, isbf) : 1.f;
#pragma unroll
  for (int i = 0; i < 4; i++) {
    int n2 = bx * 32 + ty + i * 8;
    e.dst[(long)n2 * e.K + k2] = __float2bfloat16(tile[tx][ty + i * 8] * s);
  }
}

// ---------------- prep: x cast, cos/sin, om init, rs/bar zero ----------------
__global__ __launch_bounds__(256) void prep(const void* x, const void* fc,
                                            const void* fs, const void* om0,
                                            bf16* xb, float* cosf, float* sinf,
                                            bf16* om_bf, float* rs1, float* rs2,
                                            int* bar, const int* flagp) {
  long idx = (long)blockIdx.x * 256 + threadIdx.x;
  int isbf = flagp[0];
  if (idx < 8388608) { xb[idx] = __float2bfloat16(load_any(x, idx, isbf)); return; }
  long i = idx - 8388608;
  if (i < 32768) { cosf[i] = load_any(fc, i, isbf); return; }
  i -= 32768;
  if (i < 32768) { sinf[i] = load_any(fs, i, isbf); return; }
  i -= 32768;
  if (i < 1048576) { om_bf[i] = __float2bfloat16(load_any(om0, i & 524287, isbf)); return; }
  i -= 1048576;
  if (i < 1024) { rs1[i] = 0.f; return; }
  i -= 1024;
  if (i < 1024) { rs2[i] = 0.f; return; }
  i -= 1024;
  if (i < 128) bar[i] = 0;
}

// ---------------- 128x128 MFMA GEMM (qkv upfront, final wo) ----------------
__global__ __launch_bounds__(256) void gemm128(
    const bf16* __restrict__ A, const bf16* __restrict__ WT,
    void* __restrict__ out, const int* __restrict__ flagp,
    int N, int K, int out_mode) {
  __shared__ char smem[32768];
  int tid = threadIdx.x;
  int w = tid >> 6, lane = tid & 63;
  int C0 = blockIdx.x * 128, R0 = blockIdx.y * 128;
  int wm = (w >> 1) * 64, wn = (w & 1) * 64;
  int g = lane >> 4, n16 = lane & 15;
  floatx4 acc[4][4] = {};
  int lr = lane >> 3, lc = lane & 7;

  for (int k0 = 0; k0 < K; k0 += 64) {
    __syncthreads();
#pragma unroll
    for (int i = 0; i < 4; ++i) {
      int m = w * 32 + i * 8 + lr;
      int cg = lc ^ (m & 7);
      const bf16* ga = A + (size_t)(R0 + m) * K + k0 + cg * 8;
      const bf16* gb = WT + (size_t)(C0 + m) * K + k0 + cg * 8;
      __builtin_amdgcn_global_load_lds(
          (const __attribute__((address_space(1))) void*)ga,
          (__attribute__((address_space(3))) void*)(smem + (w * 32 + i * 8) * 128),
          16, 0, 0);
      __builtin_amdgcn_global_load_lds(
          (const __attribute__((address_space(1))) void*)gb,
          (__attribute__((address_space(3))) void*)(smem + 16384 + (w * 32 + i * 8) * 128),
          16, 0, 0);
    }
    __syncthreads();
#pragma unroll
    for (int kk = 0; kk < 2; ++kk) {
      short8 af[4], bfr[4];
#pragma unroll
      for (int i = 0; i < 4; ++i) {
        int ml = wm + i * 16 + n16;
        af[i] = *(const short8*)(smem + (ml * 8 + ((kk * 4 + g) ^ (ml & 7))) * 16);
        int nl = wn + i * 16 + n16;
        bfr[i] = *(const short8*)(smem + 16384 + (nl * 8 + ((kk * 4 + g) ^ (nl & 7))) * 16);
      }
#pragma unroll
      for (int i = 0; i < 4; ++i)
#pragma unroll
        for (int j = 0; j < 4; ++j)
          acc[i][j] = __builtin_amdgcn_mfma_f32_16x16x32_bf16(af[i], bfr[j], acc[i][j], 0, 0, 0);
    }
  }
  int isbf = flagp[0];
#pragma unroll
  for (int i = 0; i < 4; ++i)
#pragma unroll
    for (int j = 0; j < 4; ++j) {
      int row = R0 + wm + i * 16 + g * 4;
      int col = C0 + wn + j * 16 + n16;
#pragma unroll
      for (int rg = 0; rg < 4; ++rg) {
        float v = acc[i][j][rg];
        long off = (long)(row + rg) * N + col;
        if (out_mode == 0) ((float*)out)[off] = v;
        else if (out_mode == 1) ((f16*)out)[off] = (f16)v;
        else {
          if (isbf) ((bf16*)out)[off] = __float2bfloat16(v);
          else ((float*)out)[off] = v;
        }
      }
    }
}

// ---------------- rope (x side, all 8 slabs, upfront) ----------------
__global__ __launch_bounds__(256) void rope_x(
    const f16* __restrict__ qkv, const float* __restrict__ cosf,
    const float* __restrict__ sinf, f16* __restrict__ q_x,
    f16* __restrict__ k_x, f16* __restrict__ v_xT) {
  __shared__ f16 tile[64][72];
  int pt = blockIdx.x;  // pos tile 0..7
  int t = blockIdx.y;   // 0..7
  int bh = blockIdx.z;  // 0..31
  int b = bh >> 4, h = bh & 15;
  int tid = threadIdx.x;
  int i = tid & 31, p0 = tid >> 5;
  size_t slab = (size_t)t * 32 + bh;
#pragma unroll
  for (int j = 0; j < 8; ++j) {
    int pl = p0 + j * 8;
    int m = pt * 64 + pl;
    int pos = 512 + m;
    long base = ((long)b * 4096 + t * 512 + m) * 3072 + h * 64 + 2 * i;
    float c = cosf[pos * 32 + i], s = sinf[pos * 32 + i];
    float q0 = (float)qkv[base], q1 = (float)qkv[base + 1];
    f16x2 qw; qw.x = (f16)((q0 * c - q1 * s) * 0.125f);
    qw.y = (f16)((q0 * s + q1 * c) * 0.125f);
    *(f16x2*)(q_x + (slab * 512 + m) * 64 + 2 * i) = qw;
    float k0 = (float)qkv[base + 1024], k1 = (float)qkv[base + 1025];
    f16x2 kw; kw.x = (f16)(k0 * c - k1 * s); kw.y = (f16)(k0 * s + k1 * c);
    *(f16x2*)(k_x + (slab * 512 + m) * 64 + 2 * i) = kw;
    tile[2 * i][pl] = qkv[base + 2048];
    tile[2 * i + 1][pl] = qkv[base + 2049];
  }
  __syncthreads();
#pragma unroll
  for (int j = 0; j < 8; ++j) {
    int d = p0 + j * 8;
    f16x2 vv; vv.x = tile[d][2 * i]; vv.y = tile[d][2 * i + 1];
    *(f16x2*)(v_xT + (slab * 64 + d) * 512 + pt * 64 + 2 * i) = vv;
  }
}

// ---------------- manual grid barrier (256 co-resident blocks) ----------------
#define NBLK 256
__device__ __forceinline__ void gbar(int* bar) {
  __syncthreads();
  if (threadIdx.x == 0) {
    __threadfence();  // release
    int* cnt = bar;
    int* gen = bar + 64;
    int g = __hip_atomic_load(gen, __ATOMIC_RELAXED, __HIP_MEMORY_SCOPE_AGENT);
    int old = __hip_atomic_fetch_add(cnt, 1, __ATOMIC_ACQ_REL, __HIP_MEMORY_SCOPE_AGENT);
    if (old == NBLK - 1) {
      __hip_atomic_store(cnt, 0, __ATOMIC_RELAXED, __HIP_MEMORY_SCOPE_AGENT);
      __hip_atomic_fetch_add(gen, 1, __ATOMIC_ACQ_REL, __HIP_MEMORY_SCOPE_AGENT);
    } else {
      while (__hip_atomic_load(gen, __ATOMIC_ACQUIRE, __HIP_MEMORY_SCOPE_AGENT) == g)
        __builtin_amdgcn_s_sleep(64);
    }
    __threadfence();  // acquire
  }
  __syncthreads();
}

// ---------------- persistent scan loop (normal launch, 256 blocks) ----------
__global__ __launch_bounds__(256) void scan_loop(
    const bf16* __restrict__ wmT, const bf16* __restrict__ w13T,
    const bf16* __restrict__ w2T, const bf16* __restrict__ wkmvmT,
    const f16* __restrict__ q_x, const f16* __restrict__ k_x,
    const f16* __restrict__ v_xT, const float* __restrict__ cosf,
    const float* __restrict__ sinf, bf16* __restrict__ om_bf,
    bf16* __restrict__ outs_bf, float* __restrict__ om2a,
    float* __restrict__ g13, float* __restrict__ om2b,
    f16* __restrict__ mkv, f16* __restrict__ k_mem, f16* __restrict__ v_memT,
    float* __restrict__ rs1, float* __restrict__ rs2, int* __restrict__ bar) {
  __shared__ char smem[32768];
  int bid = blockIdx.x, tid = threadIdx.x;
  int w = tid >> 6, lane = tid & 63;
  int g = lane >> 4, n16 = lane & 15;
  int wm_ = w >> 1, wn_ = w & 1;

  for (int t = 0; t < NSTEP; ++t) {
    // ===== P1: om2a = om_bf @ wmT (64-tile) + rs1 row-sumsq =====
    {
      int C0 = (bid & 15) * 64, R0 = (bid >> 4) * 64;
      floatx4 acc[2][2] = {};
      int am0 = tid >> 3, ac0 = tid & 7;
      int am1 = (tid + 256) >> 3, ac1 = tid & 7;
      long grow0 = R0 + am0, grow1 = R0 + am1;
      long bn0 = (long)(C0 + am0) * 1024, bn1 = (long)(C0 + am1) * 1024;
      int lofa0 = (am0 * 8 + (ac0 ^ (am0 & 7))) * 16;
      int lofa1 = (am1 * 8 + (ac1 ^ (am1 & 7))) * 16;
      for (int k0 = 0; k0 < 1024; k0 += 64) {
        uint4 va0 = *(const uint4*)(om_bf + grow0 * 1024 + k0 + ac0 * 8);
        uint4 va1 = *(const uint4*)(om_bf + grow1 * 1024 + k0 + ac1 * 8);
        uint4 vb0 = *(const uint4*)(wmT + bn0 + k0 + ac0 * 8);
        uint4 vb1 = *(const uint4*)(wmT + bn1 + k0 + ac1 * 8);
        __syncthreads();
        *(uint4*)(smem + lofa0) = va0;
        *(uint4*)(smem + lofa1) = va1;
        *(uint4*)(smem + 8192 + lofa0) = vb0;
        *(uint4*)(smem + 8192 + lofa1) = vb1;
        __syncthreads();
#pragma unroll
        for (int kki = 0; kki < 2; ++kki) {
          int cb = kki * 4 + g;
          short8 af[2], bfr[2];
#pragma unroll
          for (int i = 0; i < 2; ++i) {
            int ml = wm_ * 32 + i * 16 + n16;
            af[i] = *(const short8*)(smem + (ml * 8 + (cb ^ (ml & 7))) * 16);
            int nl = wn_ * 32 + i * 16 + n16;
            bfr[i] = *(const short8*)(smem + 8192 + (nl * 8 + (cb ^ (nl & 7))) * 16);
          }
#pragma unroll
          for (int i = 0; i < 2; ++i)
#pragma unroll
            for (int j = 0; j < 2; ++j)
              acc[i][j] = __builtin_amdgcn_mfma_f32_16x16x32_bf16(af[i], bfr[j], acc[i][j], 0, 0, 0);
        }
      }
      __syncthreads();
      float* rsl = (float*)(smem + 16384);
      if (tid < 64) rsl[tid] = 0.f;
      __syncthreads();
#pragma unroll
      for (int i = 0; i < 2; ++i)
#pragma unroll
        for (int rg = 0; rg < 4; ++rg) {
          int rl = wm_ * 32 + i * 16 + g * 4 + rg;
          float sq = 0.f;
#pragma unroll
          for (int j = 0; j < 2; ++j) {
            float v = acc[i][j][rg];
            sq += v * v;
            om2a[(long)(R0 + rl) * 1024 + C0 + wn_ * 32 + j * 16 + n16] = v;
          }
          atomicAdd(&rsl[rl], sq);
        }
      __syncthreads();
      if (tid < 64) atomicAdd(&rs1[R0 + tid], rsl[tid]);
    }
    gbar(bar);

    // ===== P2: g13 = rmsnorm(om2a) @ w13T (128-tile, scale fused) =====
    for (int tile = bid; tile < 352; tile += NBLK) {
      int C0 = (tile % 44) * 128, R0 = (tile / 44) * 128;
      int wmm = (w >> 1) * 64, wnn = (w & 1) * 64;
      floatx4 acc[4][4] = {};
      int lr = lane >> 3, lc = lane & 7;
      int ams[4], acs[4];
      float sca[4];
#pragma unroll
      for (int i = 0; i < 4; ++i) {
        int id = tid + 256 * i;
        ams[i] = id >> 3;
        acs[i] = id & 7;
        sca[i] = rsqrtf(rs1[R0 + ams[i]] * (1.f / 1024.f) + 1e-5f);
      }
      for (int k0 = 0; k0 < 1024; k0 += 64) {
        uint4 av[4];
#pragma unroll
        for (int i = 0; i < 4; ++i) {
          const float* ap = om2a + (size_t)(R0 + ams[i]) * 1024 + k0 + acs[i] * 8;
          float4 x0 = *(const float4*)ap, x1 = *(const float4*)(ap + 4);
          union { bf16 b[8]; uint4 u; } pk;
          pk.b[0] = __float2bfloat16(x0.x * sca[i]);
          pk.b[1] = __float2bfloat16(x0.y * sca[i]);
          pk.b[2] = __float2bfloat16(x0.z * sca[i]);
          pk.b[3] = __float2bfloat16(x0.w * sca[i]);
          pk.b[4] = __float2bfloat16(x1.x * sca[i]);
          pk.b[5] = __float2bfloat16(x1.y * sca[i]);
          pk.b[6] = __float2bfloat16(x1.z * sca[i]);
          pk.b[7] = __float2bfloat16(x1.w * sca[i]);
          av[i] = pk.u;
        }
        __syncthreads();
#pragma unroll
        for (int i = 0; i < 4; ++i)
          *(uint4*)(smem + (ams[i] * 8 + (acs[i] ^ (ams[i] & 7))) * 16) = av[i];
#pragma unroll
        for (int i = 0; i < 4; ++i) {
          int m = w * 32 + i * 8 + lr;
          int cg = lc ^ (m & 7);
          const bf16* gb = w13T + (size_t)(C0 + m) * 1024 + k0 + cg * 8;
          __builtin_amdgcn_global_load_lds(
              (const __attribute__((address_space(1))) void*)gb,
              (__attribute__((address_space(3))) void*)(smem + 16384 + (w * 32 + i * 8) * 128),
              16, 0, 0);
        }
        __syncthreads();
#pragma unroll
        for (int kk = 0; kk < 2; ++kk) {
          short8 af[4], bfr[4];
#pragma unroll
          for (int i = 0; i < 4; ++i) {
            int ml = wmm + i * 16 + n16;
            af[i] = *(const short8*)(smem + (ml * 8 + ((kk * 4 + g) ^ (ml & 7))) * 16);
            int nl = wnn + i * 16 + n16;
            bfr[i] = *(const short8*)(smem + 16384 + (nl * 8 + ((kk * 4 + g) ^ (nl & 7))) * 16);
          }
#pragma unroll
          for (int i = 0; i < 4; ++i)
#pragma unroll
            for (int j = 0; j < 4; ++j)
              acc[i][j] = __builtin_amdgcn_mfma_f32_16x16x32_bf16(af[i], bfr[j], acc[i][j], 0, 0, 0);
        }
      }
#pragma unroll
      for (int i = 0; i < 4; ++i)
#pragma unroll
        for (int j = 0; j < 4; ++j) {
          int row = R0 + wmm + i * 16 + g * 4;
          int col = C0 + wnn + j * 16 + n16;
#pragma unroll
          for (int rg = 0; rg < 4; ++rg)
            g13[(long)(row + rg) * 5632 + col] = acc[i][j][rg];
        }
      __syncthreads();
    }
    gbar(bar);

    // ===== P3: om2b = om2a + (silu(g1)*g3) @ w2T (+rs2) =====
    {
      int C0 = (bid & 15) * 64, R0 = (bid >> 4) * 64;
      floatx4 acc[2][2] = {};
      int am0 = tid >> 3, ac0 = tid & 7;
      int am1 = (tid + 256) >> 3, ac1 = tid & 7;
      long bn0 = (long)(C0 + am0) * 2816, bn1 = (long)(C0 + am1) * 2816;
      int lofa0 = (am0 * 8 + (ac0 ^ (am0 & 7))) * 16;
      int lofa1 = (am1 * 8 + (ac1 ^ (am1 & 7))) * 16;
      for (int k0 = 0; k0 < 2816; k0 += 64) {
        uint4 va[2];
        int amv[2] = {am0, am1}, acv[2] = {ac0, ac1};
#pragma unroll
        for (int i = 0; i < 2; ++i) {
          const float* g1p = g13 + (size_t)(R0 + amv[i]) * 5632 + k0 + acv[i] * 8;
          const float* g3p = g1p + 2816;
          float4 a0 = *(const float4*)g1p, a1 = *(const float4*)(g1p + 4);
          float4 b0 = *(const float4*)g3p, b1 = *(const float4*)(g3p + 4);
          union { bf16 b[8]; uint4 u; } pk;
          pk.b[0] = __float2bfloat16(a0.x / (1.f + __expf(-a0.x)) * b0.x);
          pk.b[1] = __float2bfloat16(a0.y / (1.f + __expf(-a0.y)) * b0.y);
          pk.b[2] = __float2bfloat16(a0.z / (1.f + __expf(-a0.z)) * b0.z);
          pk.b[3] = __float2bfloat16(a0.w / (1.f + __expf(-a0.w)) * b0.w);
          pk.b[4] = __float2bfloat16(a1.x / (1.f + __expf(-a1.x)) * b1.x);
          pk.b[5] = __float2bfloat16(a1.y / (1.f + __expf(-a1.y)) * b1.y);
          pk.b[6] = __float2bfloat16(a1.z / (1.f + __expf(-a1.z)) * b1.z);
          pk.b[7] = __float2bfloat16(a1.w / (1.f + __expf(-a1.w)) * b1.w);
          va[i] = pk.u;
        }
        uint4 vb0 = *(const uint4*)(w2T + bn0 + k0 + ac0 * 8);
        uint4 vb1 = *(const uint4*)(w2T + bn1 + k0 + ac1 * 8);
        __syncthreads();
        *(uint4*)(smem + lofa0) = va[0];
        *(uint4*)(smem + lofa1) = va[1];
        *(uint4*)(smem + 8192 + lofa0) = vb0;
        *(uint4*)(smem + 8192 + lofa1) = vb1;
        __syncthreads();
#pragma unroll
        for (int kki = 0; kki < 2; ++kki) {
          int cb = kki * 4 + g;
          short8 af[2], bfr[2];
#pragma unroll
          for (int i = 0; i < 2; ++i) {
            int ml = wm_ * 32 + i * 16 + n16;
            af[i] = *(const short8*)(smem + (ml * 8 + (cb ^ (ml & 7))) * 16);
            int nl = wn_ * 32 + i * 16 + n16;
            bfr[i] = *(const short8*)(smem + 8192 + (nl * 8 + (cb ^ (nl & 7))) * 16);
          }
#pragma unroll
          for (int i = 0; i < 2; ++i)
#pragma unroll
            for (int j = 0; j < 2; ++j)
              acc[i][j] = __builtin_amdgcn_mfma_f32_16x16x32_bf16(af[i], bfr[j], acc[i][j], 0, 0, 0);
        }
      }
      __syncthreads();
      float* rsl = (float*)(smem + 16384);
      if (tid < 64) rsl[tid] = 0.f;
      __syncthreads();
#pragma unroll
      for (int i = 0; i < 2; ++i)
#pragma unroll
        for (int rg = 0; rg < 4; ++rg) {
          int rl = wm_ * 32 + i * 16 + g * 4 + rg;
          float sq = 0.f;
#pragma unroll
          for (int j = 0; j < 2; ++j) {
            long off = (long)(R0 + rl) * 1024 + C0 + wn_ * 32 + j * 16 + n16;
            float o2 = om2a[off] + acc[i][j][rg];
            om2b[off] = o2;
            sq += o2 * o2;
          }
          atomicAdd(&rsl[rl], sq);
        }
      __syncthreads();
      if (tid < 64) atomicAdd(&rs2[R0 + tid], rsl[tid]);
    }
    gbar(bar);

    // ===== P4: mkv = rmsnorm(om2b) @ wkmvmT (f16 out), 2 tiles/block =====
#pragma unroll
    for (int half = 0; half < 2; ++half) {
      int tile = bid + half * NBLK;
      int C0 = (tile & 31) * 64, R0 = (tile >> 5) * 64;
      floatx4 acc[2][2] = {};
      int am0 = tid >> 3, ac0 = tid & 7;
      int am1 = (tid + 256) >> 3, ac1 = tid & 7;
      long bn0 = (long)(C0 + am0) * 1024, bn1 = (long)(C0 + am1) * 1024;
      int lofa0 = (am0 * 8 + (ac0 ^ (am0 & 7))) * 16;
      int lofa1 = (am1 * 8 + (ac1 ^ (am1 & 7))) * 16;
      float sc0 = rsqrtf(rs2[R0 + am0] * (1.f / 1024.f) + 1e-5f);
      float sc1 = rsqrtf(rs2[R0 + am1] * (1.f / 1024.f) + 1e-5f);
      for (int k0 = 0; k0 < 1024; k0 += 64) {
        uint4 va[2];
        int amv[2] = {am0, am1}, acv[2] = {ac0, ac1};
        float scv[2] = {sc0, sc1};
#pragma unroll
        for (int i = 0; i < 2; ++i) {
          const float* ap = om2b + (size_t)(R0 + amv[i]) * 1024 + k0 + acv[i] * 8;
          float4 x0 = *(const float4*)ap, x1 = *(const float4*)(ap + 4);
          union { bf16 b[8]; uint4 u; } pk;
          pk.b[0] = __float2bfloat16(x0.x * scv[i]);
          pk.b[1] = __float2bfloat16(x0.y * scv[i]);
          pk.b[2] = __float2bfloat16(x0.z * scv[i]);
          pk.b[3] = __float2bfloat16(x0.w * scv[i]);
          pk.b[4] = __float2bfloat16(x1.x * scv[i]);
          pk.b[5] = __float2bfloat16(x1.y * scv[i]);
          pk.b[6] = __float2bfloat16(x1.z * scv[i]);
          pk.b[7] = __float2bfloat16(x1.w * scv[i]);
          va[i] = pk.u;
        }
        uint4 vb0 = *(const uint4*)(wkmvmT + bn0 + k0 + ac0 * 8);
        uint4 vb1 = *(const uint4*)(wkmvmT + bn1 + k0 + ac1 * 8);
        __syncthreads();
        *(uint4*)(smem + lofa0) = va[0];
        *(uint4*)(smem + lofa1) = va[1];
        *(uint4*)(smem + 8192 + lofa0) = vb0;
        *(uint4*)(smem + 8192 + lofa1) = vb1;
        __syncthreads();
#pragma unroll
        for (int kki = 0; kki < 2; ++kki) {
          int cb = kki * 4 + g;
          short8 af[2], bfr[2];
#pragma unroll
          for (int i = 0; i < 2; ++i) {
            int ml = wm_ * 32 + i * 16 + n16;
            af[i] = *(const short8*)(smem + (ml * 8 + (cb ^ (ml & 7))) * 16);
            int nl = wn_ * 32 + i * 16 + n16;
            bfr[i] = *(const short8*)(smem + 8192 + (nl * 8 + (cb ^ (nl & 7))) * 16);
          }
#pragma unroll
          for (int i = 0; i < 2; ++i)
#pragma unroll
            for (int j = 0; j < 2; ++j)
              acc[i][j] = __builtin_amdgcn_mfma_f32_16x16x32_bf16(af[i], bfr[j], acc[i][j], 0, 0, 0);
        }
      }
#pragma unroll
      for (int i = 0; i < 2; ++i)
#pragma unroll
        for (int j = 0; j < 2; ++j) {
          int row = R0 + wm_ * 32 + i * 16 + g * 4;
          int col = C0 + wn_ * 32 + j * 16 + n16;
#pragma unroll
          for (int rg = 0; rg < 4; ++rg)
            mkv[(long)(row + rg) * 2048 + col] = (f16)acc[i][j][rg];
        }
      __syncthreads();
    }
    gbar(bar);

    // ===== P4b: coalesced mem rope + V transpose (R4 rope_mem) =====
    {
      int pt = bid & 7, bh = bid >> 3;
      int b = bh >> 4, h = bh & 15;
      f16* tile = (f16*)smem;  // [64][72]
      int i = tid & 31, p0v = tid >> 5;
#pragma unroll
      for (int j = 0; j < 8; ++j) {
        int pl = p0v + j * 8;
        int pos = pt * 64 + pl;
        long base = ((long)(b * 512 + pos)) * 2048 + h * 64 + 2 * i;
        float cc = cosf[pos * 32 + i], ss = sinf[pos * 32 + i];
        float k0 = (float)mkv[base], k1 = (float)mkv[base + 1];
        f16x2 kw; kw.x = (f16)(k0 * cc - k1 * ss); kw.y = (f16)(k0 * ss + k1 * cc);
        *(f16x2*)(k_mem + ((size_t)bh * 512 + pos) * 64 + 2 * i) = kw;
        tile[(2 * i) * 72 + pl] = mkv[base + 1024];
        tile[(2 * i + 1) * 72 + pl] = mkv[base + 1025];
      }
      __syncthreads();
#pragma unroll
      for (int j = 0; j < 8; ++j) {
        int d = p0v + j * 8;
        f16x2 vv; vv.x = tile[d * 72 + 2 * i]; vv.y = tile[d * 72 + 2 * i + 1];
        *(f16x2*)(v_memT + ((size_t)bh * 64 + d) * 512 + pt * 64 + 2 * i) = vv;
      }
    }
    gbar(bar);

    // ===== P5: fp16 MFMA flash attention (R4 vector staging) =====
    {
      if (bid == 0) {
        rs1[tid] = 0.f; rs1[tid + 256] = 0.f; rs1[tid + 512] = 0.f; rs1[tid + 768] = 0.f;
      } else if (bid == 1) {
        rs2[tid] = 0.f; rs2[tid + 256] = 0.f; rs2[tid + 512] = 0.f; rs2[tid + 768] = 0.f;
      }
      int qt = bid & 7, bh = bid >> 3;
      int batb = bh >> 4, hh = bh & 15;
      int numc = 9 + qt;
      int pos = 512 + qt * 64 + w * 16 + n16;
      size_t slab = (size_t)t * 32 + bh;
      f16x8 qf[2];
      {
        const f16* qp = q_x + (slab * 512 + qt * 64 + w * 16 + n16) * 64 + g * 8;
        qf[0] = *(const f16x8*)(qp);
        qf[1] = *(const f16x8*)(qp + 32);
      }
      floatx4 O[4] = {};
      float mrun = -1e30f, lrun = 0.f;
      int r0 = tid >> 3, c0 = tid & 7;
      int r1 = (tid + 256) >> 3, c1 = tid & 7;
      int lof0 = ((r0 << 3) | (c0 ^ (r0 & 7))) * 16;
      int lof1 = ((r1 << 3) | (c1 ^ (r1 & 7))) * 16;

      auto kaddr = [&](int c, int r) -> const f16* {
        return (c < 8) ? k_mem + ((size_t)bh * 512 + c * 64 + r) * 64
                       : k_x + (slab * 512 + (c - 8) * 64 + r) * 64;
      };
      auto vaddr = [&](int c, int d) -> const f16* {
        return (c < 8) ? v_memT + ((size_t)bh * 64 + d) * 512 + c * 64
                       : v_xT + (slab * 64 + d) * 512 + (c - 8) * 64;
      };

      uint4 kv0 = *(const uint4*)(kaddr(0, r0) + c0 * 8);
      uint4 kv1 = *(const uint4*)(kaddr(0, r1) + c1 * 8);
      uint4 vv0 = *(const uint4*)(vaddr(0, r0) + c0 * 8);
      uint4 vv1 = *(const uint4*)(vaddr(0, r1) + c1 * 8);
      char* Pw = smem + 16384 + w * 2048;

      for (int c = 0; c < numc; ++c) {
        __syncthreads();
        *(uint4*)(smem + lof0) = kv0;
        *(uint4*)(smem + lof1) = kv1;
        *(uint4*)(smem + 8192 + lof0) = vv0;
        *(uint4*)(smem + 8192 + lof1) = vv1;
        if (c + 1 < numc) {
          kv0 = *(const uint4*)(kaddr(c + 1, r0) + c0 * 8);
          kv1 = *(const uint4*)(kaddr(c + 1, r1) + c1 * 8);
          vv0 = *(const uint4*)(vaddr(c + 1, r0) + c0 * 8);
          vv1 = *(const uint4*)(vaddr(c + 1, r1) + c1 * 8);
        }
        __syncthreads();

        floatx4 S[4] = {};
#pragma unroll
        for (int kk = 0; kk < 2; ++kk) {
#pragma unroll
          for (int tn = 0; tn < 4; ++tn) {
            int row = tn * 16 + n16;
            f16x8 kf = *(const f16x8*)(smem + (((row << 3) | ((kk * 4 + g) ^ (row & 7))) * 16));
            S[tn] = __builtin_amdgcn_mfma_f32_16x16x32_f16(kf, qf[kk], S[tn], 0, 0, 0);
          }
        }
        if (c == numc - 1) {
          int kb = 512 + (c - 8) * 64;
#pragma unroll
          for (int tn = 0; tn < 4; ++tn)
#pragma unroll
            for (int r = 0; r < 4; ++r) {
              int key = kb + tn * 16 + g * 4 + r;
              if (key > pos) S[tn][r] = -1e30f;
            }
        }
        float smax = -1e30f;
#pragma unroll
        for (int tn = 0; tn < 4; ++tn)
#pragma unroll
          for (int r = 0; r < 4; ++r) smax = fmaxf(smax, S[tn][r]);
        smax = fmaxf(smax, __shfl_xor(smax, 16));
        smax = fmaxf(smax, __shfl_xor(smax, 32));
        float newm = fmaxf(mrun, smax);
        float corr = __expf(mrun - newm);
        mrun = newm;
        float lsum = 0.f;
        f16 pv[16];
#pragma unroll
        for (int tn = 0; tn < 4; ++tn)
#pragma unroll
          for (int r = 0; r < 4; ++r) {
            float p = __expf(S[tn][r] - newm);
            lsum += p;
            pv[tn * 4 + r] = (f16)p;
          }
        lsum += __shfl_xor(lsum, 16);
        lsum += __shfl_xor(lsum, 32);
        lrun = lrun * corr + lsum;
        float cr[4];
#pragma unroll
        for (int r = 0; r < 4; ++r) cr[r] = __shfl(corr, g * 4 + r);
#pragma unroll
        for (int dt = 0; dt < 4; ++dt)
#pragma unroll
          for (int r = 0; r < 4; ++r) O[dt][r] *= cr[r];
#pragma unroll
        for (int tn = 0; tn < 4; ++tn)
#pragma unroll
          for (int r = 0; r < 4; ++r) {
            int kap = tn * 16 + g * 4 + r;
            *(f16*)(Pw + (((n16 << 3) | ((kap >> 3) ^ (n16 & 7))) * 16 + (kap & 7) * 2)) =
                pv[tn * 4 + r];
          }
#pragma unroll
        for (int kk = 0; kk < 2; ++kk) {
          f16x8 pf = *(const f16x8*)(Pw + (((n16 << 3) | ((kk * 4 + g) ^ (n16 & 7))) * 16));
#pragma unroll
          for (int dt = 0; dt < 4; ++dt) {
            int row = dt * 16 + n16;
            f16x8 vf =
                *(const f16x8*)(smem + 8192 + (((row << 3) | ((kk * 4 + g) ^ (row & 7))) * 16));
            O[dt] = __builtin_amdgcn_mfma_f32_16x16x32_f16(pf, vf, O[dt], 0, 0, 0);
          }
        }
      }
      float rl = 1.0f / lrun;
      float rlr[4];
#pragma unroll
      for (int r = 0; r < 4; ++r) rlr[r] = __shfl(rl, g * 4 + r);
#pragma unroll
      for (int dt = 0; dt < 4; ++dt)
#pragma unroll
        for (int r = 0; r < 4; ++r) {
          int qq = qt * 64 + w * 16 + g * 4 + r;
          bf16 v = __float2bfloat16(O[dt][r] * rlr[r]);
          size_t col = hh * 64 + dt * 16 + n16;
          om_bf[((size_t)(batb * 512 + qq)) * 1024 + col] = v;
          outs_bf[((size_t)(batb * 4096 + t * 512 + qq)) * 1024 + col] = v;
        }
    }
    gbar(bar);
  }
}

// ---------------- launch ----------------
extern "C" void kernel_launch(void* const* d_in, const int* in_sizes, int n_in,
                              void* d_out, int out_size, void* d_ws, size_t ws_size,
                              hipStream_t stream) {
  (void)in_sizes; (void)n_in; (void)out_size; (void)ws_size;
  const void* x   = d_in[0];
  const void* fc  = d_in[1];
  const void* fs  = d_in[2];
  const void* wq  = d_in[3];
  const void* wk  = d_in[4];
  const void* wv  = d_in[5];
  const void* wo  = d_in[6];
  const void* wm  = d_in[7];
  const void* wkm = d_in[8];
  const void* wvm = d_in[9];
  const void* w1  = d_in[10];
  const void* w3  = d_in[11];
  const void* w2  = d_in[12];
  const void* fnw = d_in[13];
  const void* mnw = d_in[14];
  const void* om0 = d_in[15];

  char* p = (char*)d_ws;
  auto alloc = [&](size_t bytes) -> char* {
    char* r = p;
    p += (bytes + 255) & ~(size_t)255;
    return r;
  };
  int*   flag    = (int*)alloc(256);
  int*   bar     = (int*)alloc(512);
  bf16*  wqkvT   = (bf16*)alloc((size_t)3 * 1048576 * 2);
  bf16*  wmT     = (bf16*)alloc((size_t)1048576 * 2);
  bf16*  wkmvmT  = (bf16*)alloc((size_t)2 * 1048576 * 2);
  bf16*  w13T    = (bf16*)alloc((size_t)2 * 2883584 * 2);
  bf16*  w2T     = (bf16*)alloc((size_t)2883584 * 2);
  bf16*  woT     = (bf16*)alloc((size_t)1048576 * 2);
  bf16*  xb      = (bf16*)alloc((size_t)8388608 * 2);
  float* cosf    = (float*)alloc((size_t)32768 * 4);
  float* sinf    = (float*)alloc((size_t)32768 * 4);
  bf16*  om_bf   = (bf16*)alloc((size_t)1048576 * 2);
  bf16*  outs_bf = (bf16*)alloc((size_t)8388608 * 2);
  f16*   q_x     = (f16*)alloc((size_t)8 * 32 * 512 * 64 * 2);
  f16*   k_x     = (f16*)alloc((size_t)8 * 32 * 512 * 64 * 2);
  f16*   v_xT    = (f16*)alloc((size_t)8 * 32 * 512 * 64 * 2);
  float* rs1     = (float*)alloc((size_t)1024 * 4);
  float* rs2     = (float*)alloc((size_t)1024 * 4);
  // shared region: qkvf_all (upfront, 50.3 MB) overlaps loop scratch (~39 MB)
  char*  shr     = alloc((size_t)8192 * 3072 * 2);
  f16*   qkvf_all = (f16*)shr;
  char*  lp = shr;
  auto lalloc = [&](size_t bytes) -> char* {
    char* r = lp;
    lp += (bytes + 255) & ~(size_t)255;
    return r;
  };
  float* om2a   = (float*)lalloc((size_t)1048576 * 4);
  float* g13    = (float*)lalloc((size_t)5767168 * 4);
  float* om2b   = (float*)lalloc((size_t)1048576 * 4);
  f16*   mkv    = (f16*)lalloc((size_t)2097152 * 2);
  f16*   k_mem  = (f16*)lalloc((size_t)1048576 * 2);
  f16*   v_memT = (f16*)lalloc((size_t)1048576 * 2);

  dim3 tb(256);
  probe_dtype<<<1, 64, 0, stream>>>(x, flag);

  // batched weight transposes (fnw folded into w1/w3; mnw into wkm/wvm)
  TArgs ta;
  int start = 0;
  auto addT = [&](int i, const void* src, const void* scl, bf16* dst, int K, int N) {
    ta.a[i].src = src; ta.a[i].scl = scl; ta.a[i].dst = dst;
    ta.a[i].K = K; ta.a[i].N = N; ta.a[i].start = start;
    start += (N / 32) * (K / 32);
  };
  addT(0, wq, nullptr, wqkvT, 1024, 1024);
  addT(1, wk, nullptr, wqkvT + 1048576, 1024, 1024);
  addT(2, wv, nullptr, wqkvT + 2 * 1048576, 1024, 1024);
  addT(3, wm, nullptr, wmT, 1024, 1024);
  addT(4, wkm, mnw, wkmvmT, 1024, 1024);
  addT(5, wvm, mnw, wkmvmT + 1048576, 1024, 1024);
  addT(6, w1, fnw, w13T, 1024, 2816);
  addT(7, w3, fnw, w13T + 2816 * 1024, 1024, 2816);
  addT(8, w2, nullptr, w2T, 2816, 1024);
  addT(9, wo, nullptr, woT, 1024, 1024);
  transpose_all<<<start, tb, 0, stream>>>(ta, flag);

  prep<<<37129, tb, 0, stream>>>(x, fc, fs, om0, xb, cosf, sinf, om_bf, rs1, rs2,
                                 bar, flag);

  // hoisted: qkv for all 8 steps, then x-side rope/V-transpose
  gemm128<<<dim3(24, 64), tb, 0, stream>>>(xb, wqkvT, qkvf_all, flag, 3072, 1024, 1);
  rope_x<<<dim3(8, 8, 32), tb, 0, stream>>>(qkvf_all, cosf, sinf, q_x, k_x, v_xT);

  // the whole 8-step scan: one persistent kernel, manual grid barrier
  scan_loop<<<dim3(NBLK), tb, 0, stream>>>(wmT, w13T, w2T, wkmvmT, q_x, k_x, v_xT,
                                           cosf, sinf, om_bf, outs_bf, om2a, g13,
                                           om2b, mkv, k_mem, v_memT, rs1, rs2, bar);

  gemm128<<<dim3(8, 64), tb, 0, stream>>>(outs_bf, woT, d_out, flag, 1024, 1024, 2);
}